// Round 8
// baseline (224.152 us; speedup 1.0000x reference)
//
#include <hip/hip_runtime.h>
#include <stdint.h>

#define DIM 768
#define NHEADS 12
#define HDIM 64
#define DHALF 32
#define NTOK 2048
#define LOG2E 1.44269504088896340736f

typedef unsigned short u16;
typedef unsigned int u32;
typedef __bf16 bf16x8 __attribute__((ext_vector_type(8)));
typedef short s16x8 __attribute__((ext_vector_type(8)));
typedef float f32x4 __attribute__((ext_vector_type(4)));

__device__ __forceinline__ f32x4 f4zero() { f32x4 z = {0.f, 0.f, 0.f, 0.f}; return z; }

// fp32 -> bf16 bits, round-to-nearest-even
__device__ __forceinline__ u16 f2bf(float f) {
    u32 u = __builtin_bit_cast(u32, f);
    u32 r = (u + 0x7FFFu + ((u >> 16) & 1u)) >> 16;
    return (u16)r;
}

// async global->LDS, 16B per lane. LDS dest = wave-uniform base + lane*16.
__device__ __forceinline__ void gld_lds16(void* lds, const void* g) {
    __builtin_amdgcn_global_load_lds((const __attribute__((address_space(1))) u32*)g,
                                     (__attribute__((address_space(3))) u32*)lds,
                                     16, 0, 0);
}

// ---------------------------------------------------------------------------
// fused fp32 -> bf16 cast of x, w_qkv, w_proj (one launch)
// ---------------------------------------------------------------------------
__global__ __launch_bounds__(256) void cast3_f32_to_bf16(const float* __restrict__ a, u16* __restrict__ oa, int na4,
                                                         const float* __restrict__ b, u16* __restrict__ ob, int nb4,
                                                         const float* __restrict__ c, u16* __restrict__ oc, int nc4) {
    int i = blockIdx.x * 256 + threadIdx.x;
    const float* src;
    u16* dst;
    int j = i;
    if (i < na4) { src = a; dst = oa; }
    else if (i < na4 + nb4) { src = b; dst = ob; j = i - na4; }
    else if (i < na4 + nb4 + nc4) { src = c; dst = oc; j = i - na4 - nb4; }
    else return;
    float4 v = ((const float4*)src)[j];
    u32 w0 = (u32)f2bf(v.x) | ((u32)f2bf(v.y) << 16);
    u32 w1 = (u32)f2bf(v.z) | ((u32)f2bf(v.w) << 16);
    ((uint2*)dst)[j] = make_uint2(w0, w1);
}

// ---------------------------------------------------------------------------
// bt-GEMM: C[M,N] = A[M,K] * B[N,K]^T (+bias), bf16 in, fp32 out.
// 128x128 tile, BK=32, 256 threads = 2x2 waves, each wave 64x64 (4x4 MFMA tiles).
// ---------------------------------------------------------------------------
__global__ __launch_bounds__(256) void gemm_bt(const u16* __restrict__ A, const u16* __restrict__ Bm,
                                               float* __restrict__ C, const float* __restrict__ bias,
                                               int M, int N, int K) {
    __shared__ __align__(16) u16 sA[128 * 32];
    __shared__ __align__(16) u16 sB[128 * 32];
    const int t = threadIdx.x;
    const int wave = t >> 6, lane = t & 63;
    const int quad = lane >> 4, l16 = lane & 15;
    const int bm = blockIdx.y * 128, bn = blockIdx.x * 128;
    const int wr = wave >> 1, wc = wave & 1;

    f32x4 acc[4][4];
#pragma unroll
    for (int i = 0; i < 4; i++)
#pragma unroll
        for (int j = 0; j < 4; j++) acc[i][j] = f4zero();

    for (int k0 = 0; k0 < K; k0 += 32) {
#pragma unroll
        for (int r = 0; r < 2; ++r) {
            int c = (r * 4 + wave) * 64 + lane;
            int row = c >> 2, kc = c & 3;
            gld_lds16((char*)sA + (size_t)(r * 4 + wave) * 1024,
                      A + (size_t)(bm + row) * K + k0 + kc * 8);
            gld_lds16((char*)sB + (size_t)(r * 4 + wave) * 1024,
                      Bm + (size_t)(bn + row) * K + k0 + kc * 8);
        }
        __syncthreads();
        bf16x8 af[4], bfr[4];
#pragma unroll
        for (int mb = 0; mb < 4; mb++)
            af[mb] = *(const bf16x8*)(sA + (wr * 64 + mb * 16 + l16) * 32 + quad * 8);
#pragma unroll
        for (int nb = 0; nb < 4; nb++)
            bfr[nb] = *(const bf16x8*)(sB + (wc * 64 + nb * 16 + l16) * 32 + quad * 8);
#pragma unroll
        for (int mb = 0; mb < 4; mb++)
#pragma unroll
            for (int nb = 0; nb < 4; nb++)
                acc[mb][nb] = __builtin_amdgcn_mfma_f32_16x16x32_bf16(af[mb], bfr[nb], acc[mb][nb], 0, 0, 0);
        __syncthreads();
    }
#pragma unroll
    for (int mb = 0; mb < 4; mb++)
#pragma unroll
        for (int nb = 0; nb < 4; nb++) {
            int col = bn + wc * 64 + nb * 16 + l16;
            float bv = bias ? bias[col] : 0.f;
#pragma unroll
            for (int r = 0; r < 4; r++) {
                int row = bm + wr * 64 + mb * 16 + quad * 4 + r;
                C[(size_t)row * N + col] = acc[mb][nb][r] + bv;
            }
        }
}

// ---------------------------------------------------------------------------
// prep = fused RoPE(q,k) + V pack. One launch, two block-uniform paths.
//
// K packed FRAGMENT-MAJOR per 64-key tile:
//   k_s[bh][tile(32)][sub(8)=g*2+kc][lane(64)=quad*16+k16][j(8)]
//   element = K[key=g*16+k16][d=kc*32+quad*8+j]  -> flash reads b128 at lane*16B.
// V packed FRAGMENT-MAJOR per 32-key chunk:
//   vT[bh][chunk(64)][db(4)][lane(64)=q*16+l16][jj(8)]
//   element = V[key=chunk*32+(jj<4?4q+jj:16+4q+jj-4)][d=db*16+l16]
// q: [B,H,N,64] row-major; scale 0.125*log2e folded into q.
// ---------------------------------------------------------------------------
__global__ __launch_bounds__(256) void prep(const float* __restrict__ qkv,
                                            const float* __restrict__ voxel,
                                            const float* __restrict__ theta,
                                            const int* __restrict__ gh_p, const int* __restrict__ gw_p,
                                            u16* __restrict__ q_s, u16* __restrict__ k_s,
                                            u16* __restrict__ vT, int B, int nrope) {
    __shared__ u16 tile[64][66];
    int bid = blockIdx.x;
    int t = threadIdx.x;
    if (bid < nrope) {
        // ---- RoPE path ----
        int tid = bid * 256 + t;
        int d = tid & (DHALF - 1);
        int n = (tid >> 5) & (NTOK - 1);
        int hb = tid >> 16;  // 32*2048 = 65536 per (b,h)
        int h = hb % NHEADS;
        int b = hb / NHEADS;
        int gh = *gh_p, gw = *gw_p;
        int xw = n % gw;
        int rem = n / gw;
        int yh = rem % gh;
        int zd = rem / gh;
        int axis = d % 3;
        float coordv = (axis == 0 ? (float)zd : (axis == 1 ? (float)yh : (float)xw)) * voxel[axis];
        float ang = coordv * theta[h * DHALF + d];
        float s, c;
        __sincosf(ang, &s, &c);
        size_t bi = ((size_t)b * NTOK + n) * (3 * DIM);
        const float* qp = qkv + bi + h * HDIM;
        float q1 = qp[d], q2 = qp[d + DHALF];
        float k1 = qp[DIM + d], k2 = qp[DIM + d + DHALF];
        size_t bh = (size_t)b * NHEADS + h;
        size_t bo = (bh * NTOK + n) * HDIM;
        const float qscale = 0.125f * LOG2E;
        q_s[bo + d] = f2bf((q1 * c - q2 * s) * qscale);
        q_s[bo + d + DHALF] = f2bf((q1 * s + q2 * c) * qscale);
        int tile_i = n >> 6, r = n & 63, g = r >> 4, k16 = r & 15;
        int qd = d >> 3, j = d & 7;  // d < 32
        size_t off = bh * NTOK * HDIM + (size_t)tile_i * 4096 +
                     (size_t)(g * 2) * 512 + (qd * 16 + k16) * 8 + j;
        k_s[off] = f2bf(k1 * c - k2 * s);        // kc = 0 (dims 0..31)
        k_s[off + 512] = f2bf(k1 * s + k2 * c);  // kc = 1 (dims 32..63)
    } else {
        // ---- V pack path ----
        int idx = bid - nrope;
        int nt = idx & 31;             // NTOK/64 tiles
        int rem = idx >> 5;
        int h = rem % NHEADS, b = rem / NHEADS;
        int n_loc = t >> 2, d0 = (t & 3) * 16;
        const float* src = qkv + ((size_t)b * NTOK + nt * 64 + n_loc) * (3 * DIM) + 2 * DIM + h * HDIM + d0;
#pragma unroll
        for (int j = 0; j < 16; j += 4) {
            float4 v = *(const float4*)(src + j);
            tile[n_loc][d0 + j + 0] = f2bf(v.x);
            tile[n_loc][d0 + j + 1] = f2bf(v.y);
            tile[n_loc][d0 + j + 2] = f2bf(v.z);
            tile[n_loc][d0 + j + 3] = f2bf(v.w);
        }
        __syncthreads();
        int db = t >> 6, l = t & 63, q = (t >> 4) & 3, l16 = t & 15;
        int dd = db * 16 + l16;
        size_t bh = (size_t)b * NHEADS + h;
#pragma unroll
        for (int c = 0; c < 2; c++) {
            u32 w[4];
#pragma unroll
            for (int jp = 0; jp < 4; jp++) {
                int jj0 = jp * 2, jj1 = jp * 2 + 1;
                int key0 = c * 32 + (jj0 < 4 ? 4 * q + jj0 : 16 + 4 * q + jj0 - 4);
                int key1 = c * 32 + (jj1 < 4 ? 4 * q + jj1 : 16 + 4 * q + jj1 - 4);
                w[jp] = (u32)tile[key0][dd] | ((u32)tile[key1][dd] << 16);
            }
            u16* dst = vT + ((bh * 64 + (size_t)nt * 2 + c) * 2048 + db * 512 + (size_t)l * 8);
            *(uint4*)dst = make_uint4(w[0], w[1], w[2], w[3]);
        }
    }
}

// ---------------------------------------------------------------------------
// Flash attention v8: WG = 2 waves x 32 q-rows = 64 rows; grid 768 = exactly
// 3 WGs/CU (perfect balance, 6 waves/CU -> barrier/DMA stalls of one WG hide
// under compute of the other two). K/V shared across the 2 waves via
// double-buffered global_load_lds (32KB LDS/WG, one barrier per iter).
// Fragment-major K/V: all ds_read_b128 at base+lane*16 -> zero bank conflicts.
// All-register P path (S^T = K*Q^T; exp2; feed PV as A-frag), ones-column
// row-sum MFMA, fixed-base softmax. %NBH swizzle keeps each bh on one XCD.
// ---------------------------------------------------------------------------
__global__ __launch_bounds__(128) void flash_attn(const u16* __restrict__ Q, const u16* __restrict__ Kp,
                                                  const u16* __restrict__ Vp, u16* __restrict__ Out, int NBH) {
    int i = blockIdx.x;
    int bh_i = i % NBH;
    int qt = i / NBH;  // 0..31
    int b = bh_i / NHEADS, h = bh_i % NHEADS;
    int t = threadIdx.x, wave = t >> 6, lane = t & 63, quad = lane >> 4, l16 = lane & 15;
    size_t bh = (size_t)b * NHEADS + h;
    const u16* Qb = Q + bh * NTOK * HDIM;
    const u16* Kb = Kp + bh * NTOK * HDIM;  // frag-major 4096-elem tiles
    const u16* Vb = Vp + bh * NTOK * HDIM;  // frag-major: 2 chunks x 2048 per tile

    __shared__ __align__(16) u16 smem[2][8192];  // [buf][K 4096 | V 4096] = 32KB

    const int q0 = qt * 64 + wave * 32;
    bf16x8 qf[2][2];
#pragma unroll
    for (int qb = 0; qb < 2; qb++)
#pragma unroll
        for (int kc = 0; kc < 2; kc++)
            qf[qb][kc] = *(const bf16x8*)(Qb + (size_t)(q0 + qb * 16 + l16) * HDIM + kc * 32 + quad * 8);

    // ones B-frag: col 0 accumulates the P row-sum
    s16x8 ov;
#pragma unroll
    for (int j = 0; j < 8; j++) ov[j] = (l16 == 0) ? (short)0x3F80 : (short)0;

    f32x4 o[2][5];
#pragma unroll
    for (int qb = 0; qb < 2; qb++)
#pragma unroll
        for (int db = 0; db < 5; db++) o[qb][db] = f4zero();

    // stage 8KB K + 8KB V of tile kt into buffer bi (8 x 1KB DMA per wave)
    auto stage = [&](int kt, int bi) {
        const u16* Kg = Kb + (size_t)kt * 4096;
        const u16* Vg = Vb + (size_t)kt * 4096;
        u16* buf = &smem[bi][0];
#pragma unroll
        for (int s = 0; s < 4; s++) {
            gld_lds16(buf + (wave * 4 + s) * 512, Kg + (wave * 4 + s) * 512 + lane * 8);
            gld_lds16(buf + 4096 + (wave * 4 + s) * 512, Vg + (wave * 4 + s) * 512 + lane * 8);
        }
    };

    stage(0, 0);
    int cur = 0;
    for (int kt = 0; kt < NTOK / 64; ++kt) {
        __syncthreads();  // drains DMA of buf[cur]; protects buf[cur^1] reuse
        if (kt + 1 < NTOK / 64) stage(kt + 1, cur ^ 1);
        const u16* sK = &smem[cur][0];
        const u16* sV = &smem[cur][4096];
#pragma unroll
        for (int c = 0; c < 2; ++c) {
            bf16x8 kf[2][2];
#pragma unroll
            for (int kb2 = 0; kb2 < 2; kb2++)
#pragma unroll
                for (int kc = 0; kc < 2; kc++)
                    kf[kb2][kc] = *(const bf16x8*)(sK + ((c * 2 + kb2) * 2 + kc) * 512 + lane * 8);
            s16x8 bv[4];
#pragma unroll
            for (int db = 0; db < 4; db++)
                bv[db] = *(const s16x8*)(sV + c * 2048 + db * 512 + lane * 8);
#pragma unroll
            for (int qb = 0; qb < 2; qb++) {
                f32x4 st0, st1;
                {
                    f32x4 z = f4zero();
                    z = __builtin_amdgcn_mfma_f32_16x16x32_bf16(kf[0][0], qf[qb][0], z, 0, 0, 0);
                    st0 = __builtin_amdgcn_mfma_f32_16x16x32_bf16(kf[0][1], qf[qb][1], z, 0, 0, 0);
                    f32x4 z2 = f4zero();
                    z2 = __builtin_amdgcn_mfma_f32_16x16x32_bf16(kf[1][0], qf[qb][0], z2, 0, 0, 0);
                    st1 = __builtin_amdgcn_mfma_f32_16x16x32_bf16(kf[1][1], qf[qb][1], z2, 0, 0, 0);
                }
                bf16x8 pb;
#pragma unroll
                for (int r = 0; r < 4; r++) {
                    pb[r] = (__bf16)__builtin_exp2f(st0[r]);
                    pb[r + 4] = (__bf16)__builtin_exp2f(st1[r]);
                }
#pragma unroll
                for (int db = 0; db < 4; db++)
                    o[qb][db] = __builtin_amdgcn_mfma_f32_16x16x32_bf16(pb, __builtin_bit_cast(bf16x8, bv[db]),
                                                                       o[qb][db], 0, 0, 0);
                o[qb][4] = __builtin_amdgcn_mfma_f32_16x16x32_bf16(pb, __builtin_bit_cast(bf16x8, ov),
                                                                  o[qb][4], 0, 0, 0);
            }
        }
        cur ^= 1;
    }

    // epilogue: broadcast row-sum from col-0 lanes, normalize, store bf16
#pragma unroll
    for (int qb = 0; qb < 2; qb++)
#pragma unroll
        for (int r = 0; r < 4; r++) {
            float s = __shfl(o[qb][4][r], lane & 48);  // lane quad*16 holds the sum
            float inv = 1.0f / s;
            int n = q0 + qb * 16 + quad * 4 + r;
            u16* dst = Out + ((size_t)b * NTOK + n) * DIM + h * HDIM + l16;
#pragma unroll
            for (int db = 0; db < 4; db++)
                dst[db * 16] = f2bf(o[qb][db][r] * inv);
        }
}

// ---------------------------------------------------------------------------
extern "C" void kernel_launch(void* const* d_in, const int* in_sizes, int n_in,
                              void* d_out, int out_size, void* d_ws, size_t ws_size,
                              hipStream_t stream) {
    const float* x = (const float*)d_in[0];
    const float* voxel = (const float*)d_in[1];
    const float* w_qkv = (const float*)d_in[2];
    const float* w_proj = (const float*)d_in[3];
    const float* b_proj = (const float*)d_in[4];
    const float* theta = (const float*)d_in[5];
    const int* gh_p = (const int*)d_in[7];
    const int* gw_p = (const int*)d_in[8];
    const int B = in_sizes[0] / (NTOK * DIM);
    const int M = B * NTOK;

    char* p = (char*)d_ws;
    u16* xb = (u16*)p;       p += (size_t)M * DIM * 2;
    u16* wqkvb = (u16*)p;    p += (size_t)3 * DIM * DIM * 2;
    u16* wprojb = (u16*)p;   p += (size_t)DIM * DIM * 2;
    float* qkv = (float*)p;  p += (size_t)M * 3 * DIM * 4;
    u16* q_s = (u16*)p;      p += (size_t)M * DIM * 2;
    u16* k_s = (u16*)p;      p += (size_t)M * DIM * 2;
    u16* vT = (u16*)p;       p += (size_t)M * DIM * 2;
    u16* attn = (u16*)p;     p += (size_t)M * DIM * 2;

    int na4 = M * DIM / 4, nb4 = 3 * DIM * DIM / 4, nc4 = DIM * DIM / 4;
    cast3_f32_to_bf16<<<dim3((na4 + nb4 + nc4 + 255) / 256), 256, 0, stream>>>(
        x, xb, na4, w_qkv, wqkvb, nb4, w_proj, wprojb, nc4);

    gemm_bt<<<dim3(3 * DIM / 128, M / 128), 256, 0, stream>>>(xb, wqkvb, qkv, nullptr, M, 3 * DIM, DIM);

    int nrope = (B * NHEADS * NTOK * DHALF) / 256;
    int nvt = B * NHEADS * (NTOK / 64);
    prep<<<dim3(nrope + nvt), 256, 0, stream>>>(qkv, voxel, theta, gh_p, gw_p, q_s, k_s, vT, B, nrope);

    flash_attn<<<dim3((B * NHEADS * NTOK) / 64), 128, 0, stream>>>(q_s, k_s, vT, attn, B * NHEADS);

    gemm_bt<<<dim3(DIM / 128, M / 128), 256, 0, stream>>>(attn, wprojb, (float*)d_out, b_proj, M, DIM, DIM);
}

// Round 9
// 204.894 us; speedup vs baseline: 1.0940x; 1.0940x over previous
//
#include <hip/hip_runtime.h>
#include <stdint.h>

#define DIM 768
#define NHEADS 12
#define HDIM 64
#define DHALF 32
#define NTOK 2048
#define LOG2E 1.44269504088896340736f

typedef unsigned short u16;
typedef unsigned int u32;
typedef __bf16 bf16x8 __attribute__((ext_vector_type(8)));
typedef short s16x8 __attribute__((ext_vector_type(8)));
typedef float f32x4 __attribute__((ext_vector_type(4)));

__device__ __forceinline__ f32x4 f4zero() { f32x4 z = {0.f, 0.f, 0.f, 0.f}; return z; }

// fp32 -> bf16 bits, round-to-nearest-even
__device__ __forceinline__ u16 f2bf(float f) {
    u32 u = __builtin_bit_cast(u32, f);
    u32 r = (u + 0x7FFFu + ((u >> 16) & 1u)) >> 16;
    return (u16)r;
}

// async global->LDS, 16B per lane. LDS dest = wave-uniform base + lane*16.
__device__ __forceinline__ void gld_lds16(void* lds, const void* g) {
    __builtin_amdgcn_global_load_lds((const __attribute__((address_space(1))) u32*)g,
                                     (__attribute__((address_space(3))) u32*)lds,
                                     16, 0, 0);
}

// ---------------------------------------------------------------------------
// fused fp32 -> bf16 cast of x, w_qkv, w_proj (one launch)
// ---------------------------------------------------------------------------
__global__ __launch_bounds__(256) void cast3_f32_to_bf16(const float* __restrict__ a, u16* __restrict__ oa, int na4,
                                                         const float* __restrict__ b, u16* __restrict__ ob, int nb4,
                                                         const float* __restrict__ c, u16* __restrict__ oc, int nc4) {
    int i = blockIdx.x * 256 + threadIdx.x;
    const float* src;
    u16* dst;
    int j = i;
    if (i < na4) { src = a; dst = oa; }
    else if (i < na4 + nb4) { src = b; dst = ob; j = i - na4; }
    else if (i < na4 + nb4 + nc4) { src = c; dst = oc; j = i - na4 - nb4; }
    else return;
    float4 v = ((const float4*)src)[j];
    u32 w0 = (u32)f2bf(v.x) | ((u32)f2bf(v.y) << 16);
    u32 w1 = (u32)f2bf(v.z) | ((u32)f2bf(v.w) << 16);
    ((uint2*)dst)[j] = make_uint2(w0, w1);
}

// ---------------------------------------------------------------------------
// bt-GEMM: C[M,N] = A[M,K] * B[N,K]^T (+bias), bf16 in, fp32 out.
// 128x128 tile, BK=32, 256 threads = 2x2 waves, each wave 64x64 (4x4 MFMA tiles).
// ---------------------------------------------------------------------------
__global__ __launch_bounds__(256) void gemm_bt(const u16* __restrict__ A, const u16* __restrict__ Bm,
                                               float* __restrict__ C, const float* __restrict__ bias,
                                               int M, int N, int K) {
    __shared__ __align__(16) u16 sA[128 * 32];
    __shared__ __align__(16) u16 sB[128 * 32];
    const int t = threadIdx.x;
    const int wave = t >> 6, lane = t & 63;
    const int quad = lane >> 4, l16 = lane & 15;
    const int bm = blockIdx.y * 128, bn = blockIdx.x * 128;
    const int wr = wave >> 1, wc = wave & 1;

    f32x4 acc[4][4];
#pragma unroll
    for (int i = 0; i < 4; i++)
#pragma unroll
        for (int j = 0; j < 4; j++) acc[i][j] = f4zero();

    for (int k0 = 0; k0 < K; k0 += 32) {
#pragma unroll
        for (int r = 0; r < 2; ++r) {
            int c = (r * 4 + wave) * 64 + lane;
            int row = c >> 2, kc = c & 3;
            gld_lds16((char*)sA + (size_t)(r * 4 + wave) * 1024,
                      A + (size_t)(bm + row) * K + k0 + kc * 8);
            gld_lds16((char*)sB + (size_t)(r * 4 + wave) * 1024,
                      Bm + (size_t)(bn + row) * K + k0 + kc * 8);
        }
        __syncthreads();
        bf16x8 af[4], bfr[4];
#pragma unroll
        for (int mb = 0; mb < 4; mb++)
            af[mb] = *(const bf16x8*)(sA + (wr * 64 + mb * 16 + l16) * 32 + quad * 8);
#pragma unroll
        for (int nb = 0; nb < 4; nb++)
            bfr[nb] = *(const bf16x8*)(sB + (wc * 64 + nb * 16 + l16) * 32 + quad * 8);
#pragma unroll
        for (int mb = 0; mb < 4; mb++)
#pragma unroll
            for (int nb = 0; nb < 4; nb++)
                acc[mb][nb] = __builtin_amdgcn_mfma_f32_16x16x32_bf16(af[mb], bfr[nb], acc[mb][nb], 0, 0, 0);
        __syncthreads();
    }
#pragma unroll
    for (int mb = 0; mb < 4; mb++)
#pragma unroll
        for (int nb = 0; nb < 4; nb++) {
            int col = bn + wc * 64 + nb * 16 + l16;
            float bv = bias ? bias[col] : 0.f;
#pragma unroll
            for (int r = 0; r < 4; r++) {
                int row = bm + wr * 64 + mb * 16 + quad * 4 + r;
                C[(size_t)row * N + col] = acc[mb][nb][r] + bv;
            }
        }
}

// ---------------------------------------------------------------------------
// prep = fused RoPE(q,k) + V pack. One launch, two block-uniform paths.
//
// K packed FRAGMENT-MAJOR per 64-key tile:
//   k_s[bh][tile(32)][sub(8)=g*2+kc][lane(64)=quad*16+k16][j(8)]
//   element = K[key=g*16+k16][d=kc*32+quad*8+j]  -> flash reads b128 at lane*16B.
// V packed FRAGMENT-MAJOR per 32-key chunk:
//   vT[bh][chunk(64)][db(4)][lane(64)=q*16+l16][jj(8)]
//   element = V[key=chunk*32+(jj<4?4q+jj:16+4q+jj-4)][d=db*16+l16]
// q: [B,H,N,64] row-major; scale 0.125*log2e folded into q.
// ---------------------------------------------------------------------------
__global__ __launch_bounds__(256) void prep(const float* __restrict__ qkv,
                                            const float* __restrict__ voxel,
                                            const float* __restrict__ theta,
                                            const int* __restrict__ gh_p, const int* __restrict__ gw_p,
                                            u16* __restrict__ q_s, u16* __restrict__ k_s,
                                            u16* __restrict__ vT, int B, int nrope) {
    __shared__ u16 tile[64][66];
    int bid = blockIdx.x;
    int t = threadIdx.x;
    if (bid < nrope) {
        // ---- RoPE path ----
        int tid = bid * 256 + t;
        int d = tid & (DHALF - 1);
        int n = (tid >> 5) & (NTOK - 1);
        int hb = tid >> 16;  // 32*2048 = 65536 per (b,h)
        int h = hb % NHEADS;
        int b = hb / NHEADS;
        int gh = *gh_p, gw = *gw_p;
        int xw = n % gw;
        int rem = n / gw;
        int yh = rem % gh;
        int zd = rem / gh;
        int axis = d % 3;
        float coordv = (axis == 0 ? (float)zd : (axis == 1 ? (float)yh : (float)xw)) * voxel[axis];
        float ang = coordv * theta[h * DHALF + d];
        float s, c;
        __sincosf(ang, &s, &c);
        size_t bi = ((size_t)b * NTOK + n) * (3 * DIM);
        const float* qp = qkv + bi + h * HDIM;
        float q1 = qp[d], q2 = qp[d + DHALF];
        float k1 = qp[DIM + d], k2 = qp[DIM + d + DHALF];
        size_t bh = (size_t)b * NHEADS + h;
        size_t bo = (bh * NTOK + n) * HDIM;
        const float qscale = 0.125f * LOG2E;
        q_s[bo + d] = f2bf((q1 * c - q2 * s) * qscale);
        q_s[bo + d + DHALF] = f2bf((q1 * s + q2 * c) * qscale);
        int tile_i = n >> 6, r = n & 63, g = r >> 4, k16 = r & 15;
        int qd = d >> 3, j = d & 7;  // d < 32
        size_t off = bh * NTOK * HDIM + (size_t)tile_i * 4096 +
                     (size_t)(g * 2) * 512 + (qd * 16 + k16) * 8 + j;
        k_s[off] = f2bf(k1 * c - k2 * s);        // kc = 0 (dims 0..31)
        k_s[off + 512] = f2bf(k1 * s + k2 * c);  // kc = 1 (dims 32..63)
    } else {
        // ---- V pack path ----
        int idx = bid - nrope;
        int nt = idx & 31;             // NTOK/64 tiles
        int rem = idx >> 5;
        int h = rem % NHEADS, b = rem / NHEADS;
        int n_loc = t >> 2, d0 = (t & 3) * 16;
        const float* src = qkv + ((size_t)b * NTOK + nt * 64 + n_loc) * (3 * DIM) + 2 * DIM + h * HDIM + d0;
#pragma unroll
        for (int j = 0; j < 16; j += 4) {
            float4 v = *(const float4*)(src + j);
            tile[n_loc][d0 + j + 0] = f2bf(v.x);
            tile[n_loc][d0 + j + 1] = f2bf(v.y);
            tile[n_loc][d0 + j + 2] = f2bf(v.z);
            tile[n_loc][d0 + j + 3] = f2bf(v.w);
        }
        __syncthreads();
        int db = t >> 6, l = t & 63, q = (t >> 4) & 3, l16 = t & 15;
        int dd = db * 16 + l16;
        size_t bh = (size_t)b * NHEADS + h;
#pragma unroll
        for (int c = 0; c < 2; c++) {
            u32 w[4];
#pragma unroll
            for (int jp = 0; jp < 4; jp++) {
                int jj0 = jp * 2, jj1 = jp * 2 + 1;
                int key0 = c * 32 + (jj0 < 4 ? 4 * q + jj0 : 16 + 4 * q + jj0 - 4);
                int key1 = c * 32 + (jj1 < 4 ? 4 * q + jj1 : 16 + 4 * q + jj1 - 4);
                w[jp] = (u32)tile[key0][dd] | ((u32)tile[key1][dd] << 16);
            }
            u16* dst = vT + ((bh * 64 + (size_t)nt * 2 + c) * 2048 + db * 512 + (size_t)l * 8);
            *(uint4*)dst = make_uint4(w[0], w[1], w[2], w[3]);
        }
    }
}

// ---------------------------------------------------------------------------
// Flash attention v9 = R6's winning shape + frag-major layout + dbuf:
// WG = 4 waves x 32 q-rows = 128 rows; grid 384 (1.5 WG/CU, 6 waves/CU);
// %NBH swizzle keeps each bh on one XCD. K/V staged once per WG via
// double-buffered global_load_lds (32KB LDS, ONE barrier/iter; stage kt+1
// issued right after the barrier so DMA overlaps the whole compute phase).
// Fragment-major K/V: every ds_read_b128 at base+lane*16 -> ZERO bank
// conflicts (R6 lost ~65% of its cycles to 8-way conflicts here).
// All-register P path (S^T = K*Q^T; exp2; feed PV as A-frag), ones-column
// row-sum MFMA, fixed-base softmax.
// ---------------------------------------------------------------------------
__global__ __launch_bounds__(256) void flash_attn(const u16* __restrict__ Q, const u16* __restrict__ Kp,
                                                  const u16* __restrict__ Vp, u16* __restrict__ Out, int NBH) {
    int i = blockIdx.x;
    int bh_i = i % NBH;
    int qt = i / NBH;  // 0..15
    int b = bh_i / NHEADS, h = bh_i % NHEADS;
    int t = threadIdx.x, wave = t >> 6, lane = t & 63, quad = lane >> 4, l16 = lane & 15;
    size_t bh = (size_t)b * NHEADS + h;
    const u16* Qb = Q + bh * NTOK * HDIM;
    const u16* Kb = Kp + bh * NTOK * HDIM;  // frag-major 4096-elem tiles
    const u16* Vb = Vp + bh * NTOK * HDIM;  // frag-major: 2 chunks x 2048 per tile

    __shared__ __align__(16) u16 smem[2][8192];  // [buf][K 4096 | V 4096] = 32KB

    const int q0 = qt * 128 + wave * 32;
    bf16x8 qf[2][2];
#pragma unroll
    for (int qb = 0; qb < 2; qb++)
#pragma unroll
        for (int kc = 0; kc < 2; kc++)
            qf[qb][kc] = *(const bf16x8*)(Qb + (size_t)(q0 + qb * 16 + l16) * HDIM + kc * 32 + quad * 8);

    // ones B-frag: col 0 accumulates the P row-sum
    s16x8 ov;
#pragma unroll
    for (int j = 0; j < 8; j++) ov[j] = (l16 == 0) ? (short)0x3F80 : (short)0;

    f32x4 o[2][5];
#pragma unroll
    for (int qb = 0; qb < 2; qb++)
#pragma unroll
        for (int db = 0; db < 5; db++) o[qb][db] = f4zero();

    // stage 8KB K + 8KB V of tile kt into buffer bi (4 x 1KB DMA per wave)
    auto stage = [&](int kt, int bi) {
        const u16* Kg = Kb + (size_t)kt * 4096;
        const u16* Vg = Vb + (size_t)kt * 4096;
        u16* buf = &smem[bi][0];
#pragma unroll
        for (int s = 0; s < 2; s++) {
            gld_lds16(buf + (wave * 2 + s) * 512, Kg + (wave * 2 + s) * 512 + lane * 8);
            gld_lds16(buf + 4096 + (wave * 2 + s) * 512, Vg + (wave * 2 + s) * 512 + lane * 8);
        }
    };

    stage(0, 0);
    int cur = 0;
    for (int kt = 0; kt < NTOK / 64; ++kt) {
        __syncthreads();  // drains DMA of buf[cur]; protects buf[cur^1] reuse
        if (kt + 1 < NTOK / 64) stage(kt + 1, cur ^ 1);
        const u16* sK = &smem[cur][0];
        const u16* sV = &smem[cur][4096];
#pragma unroll
        for (int c = 0; c < 2; ++c) {
            bf16x8 kf[2][2];
#pragma unroll
            for (int kb2 = 0; kb2 < 2; kb2++)
#pragma unroll
                for (int kc = 0; kc < 2; kc++)
                    kf[kb2][kc] = *(const bf16x8*)(sK + ((c * 2 + kb2) * 2 + kc) * 512 + lane * 8);
            s16x8 bv[4];
#pragma unroll
            for (int db = 0; db < 4; db++)
                bv[db] = *(const s16x8*)(sV + c * 2048 + db * 512 + lane * 8);
#pragma unroll
            for (int qb = 0; qb < 2; qb++) {
                f32x4 st0, st1;
                {
                    f32x4 z = f4zero();
                    z = __builtin_amdgcn_mfma_f32_16x16x32_bf16(kf[0][0], qf[qb][0], z, 0, 0, 0);
                    st0 = __builtin_amdgcn_mfma_f32_16x16x32_bf16(kf[0][1], qf[qb][1], z, 0, 0, 0);
                    f32x4 z2 = f4zero();
                    z2 = __builtin_amdgcn_mfma_f32_16x16x32_bf16(kf[1][0], qf[qb][0], z2, 0, 0, 0);
                    st1 = __builtin_amdgcn_mfma_f32_16x16x32_bf16(kf[1][1], qf[qb][1], z2, 0, 0, 0);
                }
                bf16x8 pb;
#pragma unroll
                for (int r = 0; r < 4; r++) {
                    pb[r] = (__bf16)__builtin_exp2f(st0[r]);
                    pb[r + 4] = (__bf16)__builtin_exp2f(st1[r]);
                }
#pragma unroll
                for (int db = 0; db < 4; db++)
                    o[qb][db] = __builtin_amdgcn_mfma_f32_16x16x32_bf16(pb, __builtin_bit_cast(bf16x8, bv[db]),
                                                                       o[qb][db], 0, 0, 0);
                o[qb][4] = __builtin_amdgcn_mfma_f32_16x16x32_bf16(pb, __builtin_bit_cast(bf16x8, ov),
                                                                  o[qb][4], 0, 0, 0);
            }
        }
        cur ^= 1;
    }

    // epilogue: broadcast row-sum from col-0 lanes, normalize, store bf16
#pragma unroll
    for (int qb = 0; qb < 2; qb++)
#pragma unroll
        for (int r = 0; r < 4; r++) {
            float s = __shfl(o[qb][4][r], lane & 48);  // lane quad*16 holds the sum
            float inv = 1.0f / s;
            int n = q0 + qb * 16 + quad * 4 + r;
            u16* dst = Out + ((size_t)b * NTOK + n) * DIM + h * HDIM + l16;
#pragma unroll
            for (int db = 0; db < 4; db++)
                dst[db * 16] = f2bf(o[qb][db][r] * inv);
        }
}

// ---------------------------------------------------------------------------
extern "C" void kernel_launch(void* const* d_in, const int* in_sizes, int n_in,
                              void* d_out, int out_size, void* d_ws, size_t ws_size,
                              hipStream_t stream) {
    const float* x = (const float*)d_in[0];
    const float* voxel = (const float*)d_in[1];
    const float* w_qkv = (const float*)d_in[2];
    const float* w_proj = (const float*)d_in[3];
    const float* b_proj = (const float*)d_in[4];
    const float* theta = (const float*)d_in[5];
    const int* gh_p = (const int*)d_in[7];
    const int* gw_p = (const int*)d_in[8];
    const int B = in_sizes[0] / (NTOK * DIM);
    const int M = B * NTOK;

    char* p = (char*)d_ws;
    u16* xb = (u16*)p;       p += (size_t)M * DIM * 2;
    u16* wqkvb = (u16*)p;    p += (size_t)3 * DIM * DIM * 2;
    u16* wprojb = (u16*)p;   p += (size_t)DIM * DIM * 2;
    float* qkv = (float*)p;  p += (size_t)M * 3 * DIM * 4;
    u16* q_s = (u16*)p;      p += (size_t)M * DIM * 2;
    u16* k_s = (u16*)p;      p += (size_t)M * DIM * 2;
    u16* vT = (u16*)p;       p += (size_t)M * DIM * 2;
    u16* attn = (u16*)p;     p += (size_t)M * DIM * 2;

    int na4 = M * DIM / 4, nb4 = 3 * DIM * DIM / 4, nc4 = DIM * DIM / 4;
    cast3_f32_to_bf16<<<dim3((na4 + nb4 + nc4 + 255) / 256), 256, 0, stream>>>(
        x, xb, na4, w_qkv, wqkvb, nb4, w_proj, wprojb, nc4);

    gemm_bt<<<dim3(3 * DIM / 128, M / 128), 256, 0, stream>>>(xb, wqkvb, qkv, nullptr, M, 3 * DIM, DIM);

    int nrope = (B * NHEADS * NTOK * DHALF) / 256;
    int nvt = B * NHEADS * (NTOK / 64);
    prep<<<dim3(nrope + nvt), 256, 0, stream>>>(qkv, voxel, theta, gh_p, gw_p, q_s, k_s, vT, B, nrope);

    flash_attn<<<dim3((B * NHEADS * NTOK) / 128), 256, 0, stream>>>(q_s, k_s, vT, attn, B * NHEADS);

    gemm_bt<<<dim3(DIM / 128, M / 128), 256, 0, stream>>>(attn, wprojb, (float*)d_out, b_proj, M, DIM, DIM);
}